// Round 4
// baseline (699.898 us; speedup 1.0000x reference)
//
#include <hip/hip_runtime.h>

typedef float v2f __attribute__((ext_vector_type(2)));

#define Bn 16
#define Sn 64
#define Cn 20
#define Tn 2048
#define TPB 256
#define KS 32
#define Kc (Tn / KS)    // 64
#define PITCH 68        // LDS row pitch in words: 16B-aligned, rows offset 4 banks -> <=2-way (free)

// One MLP layer for a PACKED pair of time points: in[c] = {x_t0, x_t1}.
// Weight is a wave-uniform s_load scalar; splat {w,w} folds into VOP3P
// op_sel so each step is ONE v_pk_fma_f32 (2 FMAs) instead of two
// v_fma_f32. This halves VALU issue, which R0-R3 showed is the binding
// resource (VALUBusy*dur == scalar-FMA issue time at 78.6 TF rate).
template <int NI, int NJ>
__device__ __forceinline__ void layerP(const v2f (&in)[NI], v2f (&out)[NJ],
                                       const float* __restrict__ W,
                                       const float* __restrict__ bb)
{
    #pragma unroll
    for (int j = 0; j < NJ; ++j) {
        const float bj = bb[j];
        v2f acc = { bj, bj };
        #pragma unroll
        for (int c = 0; c < NI; ++c) {
            const float w = W[c * NJ + j];   // uniform -> SGPR
            const v2f wv = { w, w };         // splat -> op_sel, no v_mov
            acc = __builtin_elementwise_fma(in[c], wv, acc);   // v_pk_fma_f32
        }
        const v2f z = { 0.f, 0.f };
        out[j] = __builtin_elementwise_max(acc, z);            // v_pk_max_f32
    }
}

// ---------------- Kernel A: MLP. grid = B*S*4 ----------------
__global__ __launch_bounds__(256, 4) void mlp_kernel(
    const float* __restrict__ data,
    const float* __restrict__ W1, const float* __restrict__ b1,
    const float* __restrict__ W2, const float* __restrict__ b2,
    const float* __restrict__ W3, const float* __restrict__ b3,
    const float* __restrict__ W4, const float* __restrict__ b4,
    const float* __restrict__ W5, const float* __restrict__ b5,
    float* __restrict__ y, double* __restrict__ Rp)
{
    __shared__ double rbuf[TPB / 64];

    const int tid = threadIdx.x;
    const int bs = blockIdx.x >> 2;
    const int qt = blockIdx.x & 3;
    const float* base = data + (size_t)bs * Cn * Tn;
    const int t0 = qt * (Tn / 4) + tid * 2;

    v2f x[20], h[20];
    #pragma unroll
    for (int c = 0; c < 20; ++c)
        x[c] = *(const v2f*)&base[c * Tn + t0];   // 8B aligned (t0 even)

    layerP<20, 20>(x, h, W1, b1);   // x -> h
    layerP<20, 20>(h, x, W2, b2);   // h -> x
    layerP<20, 20>(x, h, W3, b3);   // x -> h
    v2f g[10];
    layerP<20, 10>(h, g, W4, b4);   // h -> g
    v2f o[1];
    layerP<10, 1>(g, o, W5, b5);    // g -> o (final ReLU included)

    *(v2f*)&y[(size_t)bs * Tn + t0] = o[0];

    // block row-sum for the mean: wave shuffle reduce, then 4-way LDS combine
    double r = (double)o[0][0] + (double)o[0][1];
    #pragma unroll
    for (int off = 32; off > 0; off >>= 1) r += __shfl_down(r, off, 64);
    if ((tid & 63) == 0) rbuf[tid >> 6] = r;
    __syncthreads();
    if (tid == 0) Rp[blockIdx.x] = rbuf[0] + rbuf[1] + rbuf[2] + rbuf[3];
}

// ---------------- Kernel B: Gram via K-split GEMM tile + fp32 atomics ----------------
// grid = Bn * KS (=512); block stages 64 rows x Kc centered fp32 in LDS,
// each thread computes a 4x4 tile of the 64x64 Gram partial, atomicAdds to covf.
__global__ __launch_bounds__(256) void cov_kernel(
    const float* __restrict__ y, const double* __restrict__ Rp,
    float* __restrict__ covf)
{
    __shared__ __align__(16) float S[64 * PITCH];   // ~17.4 KB
    __shared__ double smean[64];

    const int tid = threadIdx.x;
    const int b  = blockIdx.x >> 5;
    const int ks = blockIdx.x & 31;

    if (tid < 64) {
        const int q = ((b << 6) + tid) * 4;
        smean[tid] = (Rp[q] + Rp[q + 1] + Rp[q + 2] + Rp[q + 3]) * (1.0 / Tn);
    }
    __syncthreads();

    // stage: 64 rows x Kc floats, centered (fp64 mean), fp32 in LDS
    const float* ybase = y + (size_t)(b << 6) * Tn + ks * Kc;
    #pragma unroll
    for (int it = 0; it < (64 * Kc / 4) / TPB; ++it) {   // 4 iters
        const int f4 = tid + it * TPB;
        const int row = f4 >> 4;                          // Kc/4 = 16 float4 per row
        const int k4 = f4 & 15;
        const float4 v = *(const float4*)&ybase[(size_t)row * Tn + k4 * 4];
        const double m = smean[row];
        float4 c;
        c.x = (float)((double)v.x - m);
        c.y = (float)((double)v.y - m);
        c.z = (float)((double)v.z - m);
        c.w = (float)((double)v.w - m);
        *(float4*)&S[row * PITCH + k4 * 4] = c;
    }
    __syncthreads();

    // compute: thread (ty,tx) -> rows {ty+16a}, cols {tx+16j}
    const int ty = tid >> 4, tx = tid & 15;
    float acc[4][4];
    #pragma unroll
    for (int a = 0; a < 4; ++a)
        #pragma unroll
        for (int j = 0; j < 4; ++j) acc[a][j] = 0.f;

    for (int kq = 0; kq < Kc / 4; ++kq) {
        float4 av[4], bv[4];
        #pragma unroll
        for (int a = 0; a < 4; ++a) av[a] = *(const float4*)&S[(ty + 16 * a) * PITCH + kq * 4];
        #pragma unroll
        for (int j = 0; j < 4; ++j) bv[j] = *(const float4*)&S[(tx + 16 * j) * PITCH + kq * 4];
        #pragma unroll
        for (int a = 0; a < 4; ++a)
            #pragma unroll
            for (int j = 0; j < 4; ++j) {
                acc[a][j] = fmaf(av[a].x, bv[j].x, acc[a][j]);
                acc[a][j] = fmaf(av[a].y, bv[j].y, acc[a][j]);
                acc[a][j] = fmaf(av[a].z, bv[j].z, acc[a][j]);
                acc[a][j] = fmaf(av[a].w, bv[j].w, acc[a][j]);
            }
    }

    float* cb = covf + ((size_t)b << 12);
    #pragma unroll
    for (int a = 0; a < 4; ++a) {
        const int row = ty + 16 * a;
        #pragma unroll
        for (int j = 0; j < 4; ++j)
            atomicAdd(&cb[(row << 6) + tx + 16 * j], acc[a][j]);
    }
}

// ---------------- Kernel C: corr + output (fp64 ratio, NaN-propagating clip) ----------------
// Note: covf is the UNSCALED Gram (no 1/(T-1)) — the scale cancels in corr.
__global__ __launch_bounds__(256) void corr_kernel(
    const float* __restrict__ covf, float* __restrict__ out)
{
    const int i = blockIdx.x * TPB + threadIdx.x;
    if (i >= Bn * Sn * Sn) return;
    const int b = i / (Sn * Sn);
    const int rem = i % (Sn * Sn);
    const int s = rem / Sn, u = rem % Sn;
    const double css = (double)covf[((size_t)b * Sn + s) * Sn + s];
    const double cuu = (double)covf[((size_t)b * Sn + u) * Sn + u];
    const double csu = (double)covf[i];
    double r = csu / sqrt(css * cuu);
    r = (r < -1.0) ? -1.0 : ((r > 1.0) ? 1.0 : r);   // NaN-propagating clip
    out[i] = (float)(1.0 - r);
}

extern "C" void kernel_launch(void* const* d_in, const int* in_sizes, int n_in,
                              void* d_out, int out_size, void* d_ws, size_t ws_size,
                              hipStream_t stream) {
    const float* data = (const float*)d_in[0];
    const float* W1 = (const float*)d_in[1];  const float* b1 = (const float*)d_in[2];
    const float* W2 = (const float*)d_in[3];  const float* b2 = (const float*)d_in[4];
    const float* W3 = (const float*)d_in[5];  const float* b3 = (const float*)d_in[6];
    const float* W4 = (const float*)d_in[7];  const float* b4 = (const float*)d_in[8];
    const float* W5 = (const float*)d_in[9];  const float* b5 = (const float*)d_in[10];
    float* out = (float*)d_out;

    // ws layout: y fp32 (8 MB) | covf fp32 (256 KB) | Rp fp64 (32 KB)
    float* y = (float*)d_ws;
    float* covf = (float*)((char*)d_ws + (size_t)Bn * Sn * Tn * sizeof(float));
    double* Rp = (double*)((char*)covf + (size_t)Bn * Sn * Sn * sizeof(float));

    hipMemsetAsync(covf, 0, (size_t)Bn * Sn * Sn * sizeof(float), stream);
    mlp_kernel<<<Bn * Sn * 4, TPB, 0, stream>>>(data, W1, b1, W2, b2, W3, b3, W4, b4, W5, b5, y, Rp);
    cov_kernel<<<Bn * KS, TPB, 0, stream>>>(y, Rp, covf);
    corr_kernel<<<(Bn * Sn * Sn + TPB - 1) / TPB, TPB, 0, stream>>>(covf, out);
}

// Round 5
// 310.576 us; speedup vs baseline: 2.2535x; 2.2535x over previous
//
#include <hip/hip_runtime.h>

#define Bn 16
#define Sn 64
#define Cn 20
#define Tn 2048
#define TPB 256
#define Mv 4            // time points per thread
#define KS 32
#define Kc (Tn / KS)    // 64
#define PITCH 68        // LDS row pitch in words: 16B-aligned, rows offset 4 banks -> <=2-way (free)

// One MLP layer for Mv=4 packed time points, j-outer / c-inner:
// one output quad of accumulators at a time; weight w = W[c*NJ+j] is a
// wave-uniform SGPR reused across 4 scalar v_fma_f32 (full-rate on
// SIMD-32). Per-weight bookkeeping (s_load/mov) amortizes over 4 FMAs
// instead of 2 — attacks the measured 2.2x VALU-issue overhead (R3:
// busy 84us vs 37.6us FMA floor).
template <int NI, int NJ>
__device__ __forceinline__ void layerM(const float (&in)[NI][Mv], float (&out)[NJ][Mv],
                                       const float* __restrict__ W,
                                       const float* __restrict__ bb)
{
    #pragma unroll
    for (int j = 0; j < NJ; ++j) {
        const float bj = bb[j];
        float a0 = bj, a1 = bj, a2 = bj, a3 = bj;
        #pragma unroll
        for (int c = 0; c < NI; ++c) {
            const float w = W[c * NJ + j];   // uniform -> SGPR operand
            a0 = fmaf(in[c][0], w, a0);
            a1 = fmaf(in[c][1], w, a1);
            a2 = fmaf(in[c][2], w, a2);
            a3 = fmaf(in[c][3], w, a3);
        }
        out[j][0] = fmaxf(a0, 0.f);
        out[j][1] = fmaxf(a1, 0.f);
        out[j][2] = fmaxf(a2, 0.f);
        out[j][3] = fmaxf(a3, 0.f);
    }
}

// ---------------- Kernel A: MLP. grid = B*S*2 (each block: 256 thr x 4 t = half row) ----
// __launch_bounds__(256, 2): register peak is genuinely ~170 (in[20][4]+out[20][4]
// live at layer boundaries); cap 256 avoids spill. VALU-bound with 4 independent
// chains/accumulator -> 2 waves/SIMD suffices.
__global__ __launch_bounds__(256, 2) void mlp_kernel(
    const float* __restrict__ data,
    const float* __restrict__ W1, const float* __restrict__ b1,
    const float* __restrict__ W2, const float* __restrict__ b2,
    const float* __restrict__ W3, const float* __restrict__ b3,
    const float* __restrict__ W4, const float* __restrict__ b4,
    const float* __restrict__ W5, const float* __restrict__ b5,
    float* __restrict__ y, double* __restrict__ Rp)
{
    __shared__ double rbuf[TPB / 64];

    const int tid = threadIdx.x;
    const int bs = blockIdx.x >> 1;
    const int half = blockIdx.x & 1;
    const float* base = data + (size_t)bs * Cn * Tn;
    const int t0 = half * (Tn / 2) + tid * Mv;

    float x[20][Mv], h[20][Mv];
    #pragma unroll
    for (int c = 0; c < 20; ++c) {
        const float4 v = *(const float4*)&base[c * Tn + t0];   // 16B aligned
        x[c][0] = v.x; x[c][1] = v.y; x[c][2] = v.z; x[c][3] = v.w;
    }

    layerM<20, 20>(x, h, W1, b1);   // x -> h
    layerM<20, 20>(h, x, W2, b2);   // h -> x
    layerM<20, 20>(x, h, W3, b3);   // x -> h
    float g[10][Mv];
    layerM<20, 10>(h, g, W4, b4);   // h -> g
    float o[1][Mv];
    layerM<10, 1>(g, o, W5, b5);    // g -> o (final ReLU included)

    float4 st; st.x = o[0][0]; st.y = o[0][1]; st.z = o[0][2]; st.w = o[0][3];
    *(float4*)&y[(size_t)bs * Tn + t0] = st;

    // block row-sum for the mean: wave shuffle reduce, then 4-way LDS combine
    double r = (double)o[0][0] + (double)o[0][1] + (double)o[0][2] + (double)o[0][3];
    #pragma unroll
    for (int off = 32; off > 0; off >>= 1) r += __shfl_down(r, off, 64);
    if ((tid & 63) == 0) rbuf[tid >> 6] = r;
    __syncthreads();
    if (tid == 0) Rp[blockIdx.x] = rbuf[0] + rbuf[1] + rbuf[2] + rbuf[3];
}

// ---------------- Kernel B: Gram via K-split GEMM tile + fp32 atomics ----------------
// grid = Bn * KS (=512); block stages 64 rows x Kc centered fp32 in LDS,
// each thread computes a 4x4 tile of the 64x64 Gram partial, atomicAdds to covf.
// Rp now has 2 partials per (b,s) row (grid of kernel A = B*S*2).
__global__ __launch_bounds__(256) void cov_kernel(
    const float* __restrict__ y, const double* __restrict__ Rp,
    float* __restrict__ covf)
{
    __shared__ __align__(16) float S[64 * PITCH];   // ~17.4 KB
    __shared__ double smean[64];

    const int tid = threadIdx.x;
    const int b  = blockIdx.x >> 5;
    const int ks = blockIdx.x & 31;

    if (tid < 64) {
        const int q = ((b << 6) + tid) * 2;
        smean[tid] = (Rp[q] + Rp[q + 1]) * (1.0 / Tn);
    }
    __syncthreads();

    // stage: 64 rows x Kc floats, centered (fp64 mean), fp32 in LDS
    const float* ybase = y + (size_t)(b << 6) * Tn + ks * Kc;
    #pragma unroll
    for (int it = 0; it < (64 * Kc / 4) / TPB; ++it) {   // 4 iters
        const int f4 = tid + it * TPB;
        const int row = f4 >> 4;                          // Kc/4 = 16 float4 per row
        const int k4 = f4 & 15;
        const float4 v = *(const float4*)&ybase[(size_t)row * Tn + k4 * 4];
        const double m = smean[row];
        float4 c;
        c.x = (float)((double)v.x - m);
        c.y = (float)((double)v.y - m);
        c.z = (float)((double)v.z - m);
        c.w = (float)((double)v.w - m);
        *(float4*)&S[row * PITCH + k4 * 4] = c;
    }
    __syncthreads();

    // compute: thread (ty,tx) -> rows {ty+16a}, cols {tx+16j}
    const int ty = tid >> 4, tx = tid & 15;
    float acc[4][4];
    #pragma unroll
    for (int a = 0; a < 4; ++a)
        #pragma unroll
        for (int j = 0; j < 4; ++j) acc[a][j] = 0.f;

    for (int kq = 0; kq < Kc / 4; ++kq) {
        float4 av[4], bv[4];
        #pragma unroll
        for (int a = 0; a < 4; ++a) av[a] = *(const float4*)&S[(ty + 16 * a) * PITCH + kq * 4];
        #pragma unroll
        for (int j = 0; j < 4; ++j) bv[j] = *(const float4*)&S[(tx + 16 * j) * PITCH + kq * 4];
        #pragma unroll
        for (int a = 0; a < 4; ++a)
            #pragma unroll
            for (int j = 0; j < 4; ++j) {
                acc[a][j] = fmaf(av[a].x, bv[j].x, acc[a][j]);
                acc[a][j] = fmaf(av[a].y, bv[j].y, acc[a][j]);
                acc[a][j] = fmaf(av[a].z, bv[j].z, acc[a][j]);
                acc[a][j] = fmaf(av[a].w, bv[j].w, acc[a][j]);
            }
    }

    float* cb = covf + ((size_t)b << 12);
    #pragma unroll
    for (int a = 0; a < 4; ++a) {
        const int row = ty + 16 * a;
        #pragma unroll
        for (int j = 0; j < 4; ++j)
            atomicAdd(&cb[(row << 6) + tx + 16 * j], acc[a][j]);
    }
}

// ---------------- Kernel C: corr + output (fp64 ratio, NaN-propagating clip) ----------------
// Note: covf is the UNSCALED Gram (no 1/(T-1)) — the scale cancels in corr.
__global__ __launch_bounds__(256) void corr_kernel(
    const float* __restrict__ covf, float* __restrict__ out)
{
    const int i = blockIdx.x * TPB + threadIdx.x;
    if (i >= Bn * Sn * Sn) return;
    const int b = i / (Sn * Sn);
    const int rem = i % (Sn * Sn);
    const int s = rem / Sn, u = rem % Sn;
    const double css = (double)covf[((size_t)b * Sn + s) * Sn + s];
    const double cuu = (double)covf[((size_t)b * Sn + u) * Sn + u];
    const double csu = (double)covf[i];
    double r = csu / sqrt(css * cuu);
    r = (r < -1.0) ? -1.0 : ((r > 1.0) ? 1.0 : r);   // NaN-propagating clip
    out[i] = (float)(1.0 - r);
}

extern "C" void kernel_launch(void* const* d_in, const int* in_sizes, int n_in,
                              void* d_out, int out_size, void* d_ws, size_t ws_size,
                              hipStream_t stream) {
    const float* data = (const float*)d_in[0];
    const float* W1 = (const float*)d_in[1];  const float* b1 = (const float*)d_in[2];
    const float* W2 = (const float*)d_in[3];  const float* b2 = (const float*)d_in[4];
    const float* W3 = (const float*)d_in[5];  const float* b3 = (const float*)d_in[6];
    const float* W4 = (const float*)d_in[7];  const float* b4 = (const float*)d_in[8];
    const float* W5 = (const float*)d_in[9];  const float* b5 = (const float*)d_in[10];
    float* out = (float*)d_out;

    // ws layout: y fp32 (8 MB) | covf fp32 (256 KB) | Rp fp64 (16 KB)
    float* y = (float*)d_ws;
    float* covf = (float*)((char*)d_ws + (size_t)Bn * Sn * Tn * sizeof(float));
    double* Rp = (double*)((char*)covf + (size_t)Bn * Sn * Sn * sizeof(float));

    hipMemsetAsync(covf, 0, (size_t)Bn * Sn * Sn * sizeof(float), stream);
    mlp_kernel<<<Bn * Sn * 2, TPB, 0, stream>>>(data, W1, b1, W2, b2, W3, b3, W4, b4, W5, b5, y, Rp);
    cov_kernel<<<Bn * KS, TPB, 0, stream>>>(y, Rp, covf);
    corr_kernel<<<(Bn * Sn * Sn + TPB - 1) / TPB, TPB, 0, stream>>>(covf, out);
}